// Round 1
// 498.259 us; speedup vs baseline: 1.2075x; 1.2075x over previous
//
#include <hip/hip_runtime.h>
#include <cstdint>

// ---------------------------------------------------------------------------
// NVFP4 fake-quant GEMM: out = fq4(x) @ fq4(w)^T + bias
// fq4: per-16-group (along K) scale = e4m3_rt(amax/6), values on e2m1 grid.
// dq = q*scale is EXACT in bf16, so we quantize into bf16 buffers in d_ws and
// run a bf16-MFMA GEMM. GEMM is the 256x256 8-phase template (T1+T2+T3+T4+T5):
// BK=64, 8 waves, double-buffered 128 KiB LDS, XOR-swizzled LDS, counted
// vmcnt(8) (never 0 in main loop), setprio around MFMA clusters.
// ---------------------------------------------------------------------------

typedef __attribute__((ext_vector_type(8))) __bf16 bf16x8;
typedef __attribute__((ext_vector_type(4))) float f32x4;

typedef __attribute__((address_space(1))) void gvoid;
typedef __attribute__((address_space(3))) void lvoid;

// Exact fp8 e4m3fn round-trip for x >= 0, x well below 448.
__device__ __forceinline__ float fp8_e4m3_rt(float x) {
    if (x < 0.015625f) {
        return __builtin_rintf(x * 512.0f) * (1.0f / 512.0f);
    }
    unsigned u = __float_as_uint(x);
    unsigned lsb = (u >> 20) & 1u;
    u = (u + 0x7FFFFu + lsb) & ~0xFFFFFu;
    return __uint_as_float(u);
}

__device__ __forceinline__ float round_e2m1(float v) {
    float a = fabsf(v);
    a = fminf(a, 6.0f);
    float q = a < 0.25f ? 0.0f :
              a < 0.75f ? 0.5f :
              a < 1.25f ? 1.0f :
              a < 1.75f ? 1.5f :
              a < 2.5f  ? 2.0f :
              a < 3.5f  ? 3.0f :
              a < 5.0f  ? 4.0f : 6.0f;
    return copysignf(q, v);
}

// One thread = 4 consecutive floats; group of 16 = 4 consecutive lanes.
__global__ __launch_bounds__(256) void quant_fp4(const float* __restrict__ in,
                                                 uint16_t* __restrict__ out,
                                                 int nquads) {
    int i = blockIdx.x * 256 + threadIdx.x;
    if (i >= nquads) return;
    float4 v = ((const float4*)in)[i];
    float a = fmaxf(fmaxf(fabsf(v.x), fabsf(v.y)), fmaxf(fabsf(v.z), fabsf(v.w)));
    a = fmaxf(a, __shfl_xor(a, 1));
    a = fmaxf(a, __shfl_xor(a, 2));
    float scale = fp8_e4m3_rt(a / 6.0f);
    float safe = scale > 0.0f ? scale : 1.0f;
    float vals[4] = {v.x, v.y, v.z, v.w};
    unsigned r[4];
    #pragma unroll
    for (int e = 0; e < 4; ++e) {
        float q = round_e2m1(vals[e] / safe);
        float dq = scale > 0.0f ? q * scale : 0.0f;
        r[e] = __float_as_uint(dq) >> 16;
    }
    uint2 o;
    o.x = r[0] | (r[1] << 16);
    o.y = r[2] | (r[3] << 16);
    ((uint2*)out)[i] = o;
}

// ---------------------------------------------------------------------------
// bf16 GEMM, C[M,N] = A[M,K] * B[N,K]^T + bias. 256x256 tile, BK=64,
// 512 threads = 8 waves (2 M x 4 N), per-wave 128x64 output = acc[8][4].
// LDS: 2 buffers x (A[256][64] + B[256][64]) bf16 = 128 KiB.
// Swizzle (T2): logical (row,k) stored at elem row*64 + (k ^ ((row&7)<<3)).
//   Staging writes LINEAR chunks (global_load_lds requirement); the global
//   SOURCE is inverse-permuted (same involution), reads apply the XOR.
// Schedule (T3/T4): 4 phases per K-tile, one C-quadrant each, order
//   (mh,nh) = (0,0),(0,1),(1,1),(1,0); B-nh0 frags held in regs to phase 3.
//   Prefetch of tile t+2 into buf[t&1] placed only after the overwritten
//   region's last ds_read phase:
//     phase1: A rows 0-63,128-191 (mh0, read ph0)
//     phase2: B rows 0-127        (nh read ph0/ph1)
//     phase3: A rows 64-127,192-255 (mh1, read ph2) + B rows 128-255
//   vmcnt ledger: 8 loads/tile; steady outstanding 16 -> vmcnt(8) at loop
//   top completes exactly tile t; vmcnt(0) only at the last tile.
// ---------------------------------------------------------------------------
#define BM 256
#define BN 256
#define BK 64
#define THREADS 512

__device__ __forceinline__ void barfence() {
    asm volatile("" ::: "memory");
    __builtin_amdgcn_s_barrier();
    asm volatile("" ::: "memory");
}

#define STG_A(bb, i, kk)                                                     \
    __builtin_amdgcn_global_load_lds((gvoid*)(Aq + (size_t)offA[i] + (kk)),  \
        (lvoid*)&lds[bb][0][ldsU + (i) * 4096], 16, 0, 0)
#define STG_B(bb, i, kk)                                                     \
    __builtin_amdgcn_global_load_lds((gvoid*)(Bq + (size_t)offB[i] + (kk)),  \
        (lvoid*)&lds[bb][1][ldsU + (i) * 4096], 16, 0, 0)

#define MFMA16(AH, BH, MH, NH)                                               \
    _Pragma("unroll")                                                        \
    for (int fi = 0; fi < 4; ++fi) {                                         \
        _Pragma("unroll")                                                    \
        for (int fj = 0; fj < 2; ++fj) {                                     \
            f32x4 c = acc[(MH) * 4 + fi][(NH) * 2 + fj];                     \
            c = __builtin_amdgcn_mfma_f32_16x16x32_bf16(AH[fi][0], BH[fj][0], c, 0, 0, 0); \
            c = __builtin_amdgcn_mfma_f32_16x16x32_bf16(AH[fi][1], BH[fj][1], c, 0, 0, 0); \
            acc[(MH) * 4 + fi][(NH) * 2 + fj] = c;                           \
        }                                                                    \
    }

__global__ __launch_bounds__(THREADS, 2)
void gemm_w4a4(const uint16_t* __restrict__ Aq, const uint16_t* __restrict__ Bq,
               const float* __restrict__ bias, float* __restrict__ C,
               int M, int N, int K) {
    __shared__ __align__(16) uint16_t lds[2][2][BM * BK];

    const int tid  = threadIdx.x;
    const int wave = tid >> 6;
    const int lane = tid & 63;
    const int wm   = wave >> 2;            // 0..1
    const int wn   = wave & 3;             // 0..3
    const int l15  = lane & 15;
    const int l7   = lane & 7;
    const int hi8  = (lane >> 4) << 3;
    const int hi4  = (lane >> 4) << 2;
    const int kx0  = hi8 ^ (l7 << 3);           // swizzled k-offset, ks=0
    const int kx1  = (32 + hi8) ^ (l7 << 3);    // swizzled k-offset, ks=1
    const int aBase = ((wm << 7) + l15) << 6;   // row*64 within A region
    const int bBase = ((wn << 6) + l15) << 6;   // row*64 within B region
    const int ldsU  = wave << 9;                // wave-uniform stage base (elems)

    // ---- tile decomposition + bijective XCD swizzle (T1, m204) ----
    const int ntm = M >> 8, ntn = N >> 8, nwg = ntm * ntn;
    const int bid = blockIdx.x;
    const int q8 = nwg >> 3, r8 = nwg & 7;
    const int xcd = bid & 7;
    const int wgid = (xcd < r8 ? xcd * (q8 + 1) : r8 * (q8 + 1) + (xcd - r8) * q8)
                     + (bid >> 3);
    const int mBase = (wgid % ntm) << 8;   // column-major: XCD shares B panel
    const int nBase = (wgid / ntm) << 8;
    (void)ntn;

    // ---- staging source offsets (inverse-swizzled, loop-invariant) ----
    // chunk c = i*512 + tid -> linear LDS elems [c*8, c*8+8);
    // holds logical row = c>>3, k = ((c&7) ^ (row&7))*8 .. +7
    uint32_t offA[4], offB[4];
    #pragma unroll
    for (int i = 0; i < 4; ++i) {
        const int c   = i * THREADS + tid;
        const int row = c >> 3;
        const int kc  = ((c & 7) ^ (row & 7)) << 3;
        offA[i] = (uint32_t)(mBase + row) * (uint32_t)K + (uint32_t)kc;
        offB[i] = (uint32_t)(nBase + row) * (uint32_t)K + (uint32_t)kc;
    }

    const int nt = K / BK;

    // ---- prologue: stage tiles 0 and 1 ----
    #pragma unroll
    for (int i = 0; i < 4; ++i) STG_A(0, i, 0);
    #pragma unroll
    for (int i = 0; i < 4; ++i) STG_B(0, i, 0);
    if (nt > 1) {
        #pragma unroll
        for (int i = 0; i < 4; ++i) STG_A(1, i, BK);
        #pragma unroll
        for (int i = 0; i < 4; ++i) STG_B(1, i, BK);
    }

    f32x4 acc[8][4] = {};

    for (int tk = 0; tk < nt; ++tk) {
        const int bb = tk & 1;
        const uint16_t* lA = &lds[bb][0][0];
        const uint16_t* lB = &lds[bb][1][0];
        const int kk = (tk + 2) * BK;
        const bool pf = (tk + 2) < nt;

        // tile tk landed; tile tk+1's 8 loads stay in flight (T4: never 0
        // in steady state)
        if (tk + 1 < nt) { asm volatile("s_waitcnt vmcnt(8)" ::: "memory"); }
        else             { asm volatile("s_waitcnt vmcnt(0)" ::: "memory"); }
        __builtin_amdgcn_s_barrier();
        asm volatile("" ::: "memory");

        bf16x8 a[4][2], b0[2][2], b1[2][2];

        // ---- phase 0: read A-mh0 (8) + B-nh0 (4); MFMA quadrant (0,0) ----
        #pragma unroll
        for (int fi = 0; fi < 4; ++fi) {
            a[fi][0] = *(const bf16x8*)&lA[aBase + fi * 1024 + kx0];
            a[fi][1] = *(const bf16x8*)&lA[aBase + fi * 1024 + kx1];
        }
        #pragma unroll
        for (int fj = 0; fj < 2; ++fj) {
            b0[fj][0] = *(const bf16x8*)&lB[bBase + fj * 1024 + kx0];
            b0[fj][1] = *(const bf16x8*)&lB[bBase + fj * 1024 + kx1];
        }
        barfence();
        __builtin_amdgcn_s_setprio(1);
        MFMA16(a, b0, 0, 0);
        __builtin_amdgcn_s_setprio(0);
        barfence();

        // ---- phase 1: read B-nh1 (4); stage A-mh0 of tile tk+2; (0,1) ----
        #pragma unroll
        for (int fj = 0; fj < 2; ++fj) {
            b1[fj][0] = *(const bf16x8*)&lB[bBase + 2048 + fj * 1024 + kx0];
            b1[fj][1] = *(const bf16x8*)&lB[bBase + 2048 + fj * 1024 + kx1];
        }
        if (pf) { STG_A(bb, 0, kk); STG_A(bb, 2, kk); }
        barfence();
        __builtin_amdgcn_s_setprio(1);
        MFMA16(a, b1, 0, 1);
        __builtin_amdgcn_s_setprio(0);
        barfence();

        // ---- phase 2: read A-mh1 (8); stage B rows 0-127; (1,1) ----
        #pragma unroll
        for (int fi = 0; fi < 4; ++fi) {
            a[fi][0] = *(const bf16x8*)&lA[aBase + 4096 + fi * 1024 + kx0];
            a[fi][1] = *(const bf16x8*)&lA[aBase + 4096 + fi * 1024 + kx1];
        }
        if (pf) { STG_B(bb, 0, kk); STG_B(bb, 1, kk); }
        barfence();
        __builtin_amdgcn_s_setprio(1);
        MFMA16(a, b1, 1, 1);
        __builtin_amdgcn_s_setprio(0);
        barfence();

        // ---- phase 3: stage A-mh1 + B rows 128-255; (1,0) reuses b0 ----
        if (pf) { STG_A(bb, 1, kk); STG_A(bb, 3, kk);
                  STG_B(bb, 2, kk); STG_B(bb, 3, kk); }
        barfence();
        __builtin_amdgcn_s_setprio(1);
        MFMA16(a, b0, 1, 0);
        __builtin_amdgcn_s_setprio(0);
        // no trailing barrier: loop-top vmcnt+barrier separates iterations
    }

    // ---- epilogue: C/D layout col = lane&15, row = (lane>>4)*4 + reg ----
    #pragma unroll
    for (int fj = 0; fj < 4; ++fj) {
        const int col = nBase + (wn << 6) + fj * 16 + l15;
        const float bj = bias[col];
        #pragma unroll
        for (int fi = 0; fi < 8; ++fi) {
            const int row0 = mBase + (wm << 7) + fi * 16 + hi4;
            #pragma unroll
            for (int rr = 0; rr < 4; ++rr)
                C[(size_t)(row0 + rr) * N + col] = acc[fi][fj][rr] + bj;
        }
    }
}

extern "C" void kernel_launch(void* const* d_in, const int* in_sizes, int n_in,
                              void* d_out, int out_size, void* d_ws, size_t ws_size,
                              hipStream_t stream) {
    const float* x    = (const float*)d_in[0];
    const float* w    = (const float*)d_in[1];
    const float* bias = (const float*)d_in[2];
    float* out = (float*)d_out;

    const int N = in_sizes[2];            // bias length
    const int K = in_sizes[1] / N;        // weight is [N,K]
    const int M = in_sizes[0] / K;        // x is [M,K]

    uint16_t* xq = (uint16_t*)d_ws;                 // M*K bf16
    uint16_t* wq = xq + (size_t)M * K;              // N*K bf16

    const int xquads = (M * K) / 4;
    const int wquads = (N * K) / 4;
    quant_fp4<<<(xquads + 255) / 256, 256, 0, stream>>>(x, xq, xquads);
    quant_fp4<<<(wquads + 255) / 256, 256, 0, stream>>>(w, wq, wquads);

    const int nwg = (M >> 8) * (N >> 8);
    gemm_w4a4<<<nwg, THREADS, 0, stream>>>(xq, wq, bias, out, M, N, K);
}